// Round 2
// baseline (10197.348 us; speedup 1.0000x reference)
//
#include <hip/hip_runtime.h>

typedef _Float16 f16;
typedef __attribute__((ext_vector_type(8))) _Float16 f16x8;
typedef __attribute__((ext_vector_type(4))) _Float16 f16x4;
typedef __attribute__((ext_vector_type(4))) float f32x4;

#define B_ 128
#define HID_ 1024
#define BH_ (B_ * HID_)   // 131072

// ------- cast + permute x: [B][T][D] f32 -> [T][B][D] f16 (B=128,T=256,D=256) -------
__global__ __launch_bounds__(256) void k_cast_x(const float* __restrict__ x,
                                                f16* __restrict__ xf) {
    size_t g = (size_t)blockIdx.x * blockDim.x + threadIdx.x;   // 2,097,152 threads
    size_t e = g * 4;
    const int d = (int)(e & 255);
    const int t = (int)((e >> 8) & 255);
    const int b = (int)(e >> 16);
    float4 v = ((const float4*)x)[g];
    f16x4 o = {(f16)v.x, (f16)v.y, (f16)v.z, (f16)v.w};
    *(f16x4*)(xf + ((size_t)t * B_ + b) * 256 + d) = o;
}

// ------- transpose + cast: src[R][srcC] f32 -> dst[srcC][dstStride] f16 (at koff) -------
__global__ __launch_bounds__(256) void k_tcast(const float* __restrict__ src,
                                               f16* __restrict__ dst,
                                               int srcC, int dstStride, int dstKoff) {
    __shared__ float tile[64][65];
    const int tx = threadIdx.x & 63, ty = threadIdx.x >> 6;
    const int r0 = blockIdx.y * 64, c0 = blockIdx.x * 64;
    #pragma unroll
    for (int r = ty; r < 64; r += 4)
        tile[r][tx] = src[(size_t)(r0 + r) * srcC + c0 + tx];
    __syncthreads();
    #pragma unroll
    for (int r = ty; r < 64; r += 4)
        dst[(size_t)(c0 + r) * dstStride + dstKoff + r0 + tx] = (f16)tile[tx][r];
}

// ---------------- prep: biases, states ----------------
__global__ __launch_bounds__(256) void k_prep(
    const float* __restrict__ bi1, const float* __restrict__ bh1,
    const float* __restrict__ bi2, const float* __restrict__ bh2,
    const float* __restrict__ h01, const float* __restrict__ c01,
    const float* __restrict__ h02, const float* __restrict__ c02,
    float* b1, float* b2, float* c1, float* c2,
    f16* h1r, f16* h2b, float* h2f) {
    int i = blockIdx.x * blockDim.x + threadIdx.x;
    if (i < 4096) { b1[i] = bi1[i] + bh1[i]; b2[i] = bi2[i] + bh2[i]; }
    if (i < BH_) {
        c1[i] = c01[i];
        c2[i] = c02[i];
        h1r[i] = (f16)h01[i];            // ring slot 0 = h1 state "after step -1"
        h2b[BH_ + i] = (f16)h02[i];      // h2 buf[1]  = h2 state "after step -1"
        h2f[i] = h02[i];
    }
}

// ---------------- one pipeline stage: layer1 step s  ||  layer2 step s-1 ----------------
// blocks 0..127: layer1 (valid s<256); blocks 128..255: layer2 (valid s>=1)
__global__ __launch_bounds__(256) void k_stage(
    int s,
    const f16* __restrict__ xall,  // [256][128][256]
    f16* h1r,                      // [2][128][1024] ring (read slot s&1, write (s+1)&1)
    const f16* __restrict__ W1T,   // [4096][1280]
    const f16* __restrict__ W2T,   // [4096][2048]
    const float* __restrict__ b1, const float* __restrict__ b2,
    float* c1, float* c2,
    f16* h2b,                      // [2][128][1024]
    float* h2f) {
    const int bid = blockIdx.x;
    const int layer = bid >> 7;
    if (layer == 0) { if (s >= 256) return; }
    else            { if (s == 0)  return; }
    const int hblk = (bid & 127) * 8;

    const f16 *A0, *A1, *WT;
    const float* bias;
    float* cbuf;
    int K0, sA0, sA1, Ktot;
    if (layer == 0) {
        A0 = xall + (size_t)s * (B_ * 256); K0 = 256; sA0 = 256;
        A1 = h1r + (size_t)(s & 1) * BH_;   sA1 = HID_;
        WT = W1T; Ktot = 1280; bias = b1; cbuf = c1;
    } else {
        A0 = h1r + (size_t)(s & 1) * BH_;   K0 = 1024; sA0 = HID_;
        A1 = h2b + (size_t)(s & 1) * BH_;   sA1 = HID_;
        WT = W2T; Ktot = 2048; bias = b2; cbuf = c2;
    }
    const int K1 = Ktot - K0;   // 1024 both layers

    const int tid = threadIdx.x;
    const int lane = tid & 63, wave = tid >> 6;
    const int mhalf = wave >> 1;      // rows 64*mhalf .. +63
    const int tilesel = wave & 1;     // gates {0,1} or {2,3}
    const int lc = lane & 15, kgrp = lane >> 4;
    const int gate = tilesel * 2 + (lc >> 3);
    const int gcol = gate * HID_ + hblk + (lc & 7);

    const f16* Bp = WT + (size_t)gcol * Ktot + kgrp * 8;
    const int rowb = mhalf * 64 + lc;

    f32x4 acc[4];
    #pragma unroll
    for (int m = 0; m < 4; ++m) acc[m] = (f32x4){0.f, 0.f, 0.f, 0.f};

    {   // phase 0: input-projection part
        const f16* Ab = A0 + (size_t)rowb * sA0 + kgrp * 8;
        for (int kk = 0; kk < K0; kk += 32) {
            f16x8 b = *(const f16x8*)(Bp + kk);
            #pragma unroll
            for (int m = 0; m < 4; ++m) {
                f16x8 a = *(const f16x8*)(Ab + kk + m * 16 * sA0);
                acc[m] = __builtin_amdgcn_mfma_f32_16x16x32_f16(a, b, acc[m], 0, 0, 0);
            }
        }
    }
    {   // phase 1: recurrent part
        const f16* Ab = A1 + (size_t)rowb * sA1 + kgrp * 8;
        const f16* Bq = Bp + K0;
        for (int kk = 0; kk < K1; kk += 32) {
            f16x8 b = *(const f16x8*)(Bq + kk);
            #pragma unroll
            for (int m = 0; m < 4; ++m) {
                f16x8 a = *(const f16x8*)(Ab + kk + m * 16 * sA1);
                acc[m] = __builtin_amdgcn_mfma_f32_16x16x32_f16(a, b, acc[m], 0, 0, 0);
            }
        }
    }

    // gate exchange: z tile [128 rows][32 cols], col = gate*8 + hid_local
    __shared__ float zl[128][33];
    #pragma unroll
    for (int m = 0; m < 4; ++m)
        #pragma unroll
        for (int j = 0; j < 4; ++j)
            zl[mhalf * 64 + m * 16 + kgrp * 4 + j][tilesel * 16 + lc] = acc[m][j];
    __syncthreads();

    // elementwise update: 128 x 8 cells, 4 per thread
    for (int e = tid; e < 1024; e += 256) {
        const int m = e >> 3, jl = e & 7;
        const int hg = hblk + jl;
        float zf = zl[m][jl]      + bias[hg];
        float zi = zl[m][8 + jl]  + bias[HID_ + hg];
        float zg = zl[m][16 + jl] + bias[2 * HID_ + hg];
        float zo = zl[m][24 + jl] + bias[3 * HID_ + hg];
        float fg = 1.f / (1.f + __expf(-zf));
        float ig = 1.f / (1.f + __expf(-zi));
        float gg = 1.f - 2.f / (__expf(2.f * zg) + 1.f);   // tanh, inf-safe
        float og = 1.f / (1.f + __expf(-zo));
        float cn = cbuf[m * HID_ + hg] * fg + ig * gg;
        cbuf[m * HID_ + hg] = cn;
        float th = 1.f - 2.f / (__expf(2.f * cn) + 1.f);
        float h = th * og;
        if (layer == 0) {
            h1r[(size_t)((s + 1) & 1) * BH_ + m * HID_ + hg] = (f16)h;
        } else {
            h2b[(size_t)((s + 1) & 1) * BH_ + m * HID_ + hg] = (f16)h;
            h2f[m * HID_ + hg] = h;
        }
    }
}

// ---------------- final: y = h2 @ Wc + bc (fp32) ----------------
__global__ __launch_bounds__(64) void k_final(const float* __restrict__ h2f,
                                              const float* __restrict__ Wc,
                                              const float* __restrict__ bc,
                                              float* __restrict__ y) {
    const int b = blockIdx.x, lane = threadIdx.x;
    float acc[10] = {0, 0, 0, 0, 0, 0, 0, 0, 0, 0};
    for (int k = lane; k < HID_; k += 64) {
        const float h = h2f[b * HID_ + k];
        #pragma unroll
        for (int j = 0; j < 10; ++j) acc[j] = fmaf(h, Wc[k * 10 + j], acc[j]);
    }
    #pragma unroll
    for (int off = 32; off; off >>= 1)
        #pragma unroll
        for (int j = 0; j < 10; ++j) acc[j] += __shfl_down(acc[j], off);
    if (lane == 0) {
        #pragma unroll
        for (int j = 0; j < 10; ++j) y[b * 10 + j] = acc[j] + bc[j];
    }
}

extern "C" void kernel_launch(void* const* d_in, const int* in_sizes, int n_in,
                              void* d_out, int out_size, void* d_ws, size_t ws_size,
                              hipStream_t stream) {
    (void)in_sizes; (void)n_in; (void)out_size; (void)ws_size;
    const float* x   = (const float*)d_in[0];
    const float* h01 = (const float*)d_in[1];
    const float* c01 = (const float*)d_in[2];
    const float* h02 = (const float*)d_in[3];
    const float* c02 = (const float*)d_in[4];
    const float* Wi1 = (const float*)d_in[5];
    const float* Wh1 = (const float*)d_in[6];
    const float* bi1 = (const float*)d_in[7];
    const float* bh1 = (const float*)d_in[8];
    const float* Wi2 = (const float*)d_in[9];
    const float* Wh2 = (const float*)d_in[10];
    const float* bi2 = (const float*)d_in[11];
    const float* bh2 = (const float*)d_in[12];
    const float* Wc  = (const float*)d_in[13];
    const float* bc  = (const float*)d_in[14];
    float* y = (float*)d_out;

    // workspace layout (bytes), total ~46.7 MB
    char* w = (char*)d_ws;
    f16*   xall = (f16*)(w + 0);            // [256][128][256] f16  = 16,777,216
    f16*   h1r  = (f16*)(w + 16777216);     // [2][128][1024] f16   =    524,288
    f16*   W1T  = (f16*)(w + 17301504);     // [4096][1280] f16     = 10,485,760
    f16*   W2T  = (f16*)(w + 27787264);     // [4096][2048] f16     = 16,777,216
    float* b1   = (float*)(w + 44564480);   // [4096] f32
    float* b2   = (float*)(w + 44580864);   // [4096] f32
    float* c1   = (float*)(w + 44597248);   // [128][1024] f32
    float* c2   = (float*)(w + 45121536);   // [128][1024] f32
    f16*   h2b  = (f16*)(w + 45645824);     // [2][128][1024] f16
    float* h2f  = (float*)(w + 46170112);   // [128][1024] f32

    k_cast_x<<<8192, 256, 0, stream>>>(x, xall);
    k_tcast<<<dim3(64, 4),  256, 0, stream>>>(Wi1, W1T, 4096, 1280, 0);
    k_tcast<<<dim3(64, 16), 256, 0, stream>>>(Wh1, W1T, 4096, 1280, 256);
    k_tcast<<<dim3(64, 16), 256, 0, stream>>>(Wi2, W2T, 4096, 2048, 0);
    k_tcast<<<dim3(64, 16), 256, 0, stream>>>(Wh2, W2T, 4096, 2048, 1024);
    k_prep<<<512, 256, 0, stream>>>(bi1, bh1, bi2, bh2, h01, c01, h02, c02,
                                    b1, b2, c1, c2, h1r, h2b, h2f);

    for (int s = 0; s <= 256; ++s)
        k_stage<<<256, 256, 0, stream>>>(s, xall, h1r, W1T, W2T, b1, b2, c1, c2, h2b, h2f);

    k_final<<<128, 64, 0, stream>>>(h2f, Wc, bc, y);
}